// Round 18
// baseline (425.415 us; speedup 1.0000x reference)
//
#include <hip/hip_runtime.h>

// Problem constants (match reference)
constexpr int NN   = 50000;          // nodes
constexpr int NE   = 800000;         // edges before self loops
constexpr int NHD  = 4;              // heads
constexpr int CC   = 32;             // channels per head
constexpr int HCC  = 128;            // NHD*CC
constexpr int NL   = 3;              // layers
constexpr int NG   = 128;            // graphs
constexpr int NOUT = 10;             // out channels
constexpr float BN_EPS = 1e-5f;

constexpr int X2S = 67;              // LDS x-row stride in packed uints (bank-safe)
constexpr int YS = 33;               // LDS y-row stride
constexpr int NSLOT = 64;            // stats slots (atomic-contention spreading)
constexpr int SCB = (NN + 1023) / 1024;   // 49 scan blocks
constexpr int NBUK = (NN + 127) / 128;    // 391 dst buckets (128 dsts each)
constexpr int EB  = 8192;            // edges per k_bin block
constexpr int FB  = 128;             // nodes per k_fused block (512 threads)

// fp32 -> bf16 (round-to-nearest-even), packed pair helpers
__device__ inline unsigned f2bf_pack(float a, float b) {
    unsigned ua = __float_as_uint(a); ua += 0x7FFFu + ((ua >> 16) & 1u);
    unsigned ub = __float_as_uint(b); ub += 0x7FFFu + ((ub >> 16) & 1u);
    return (ua >> 16) | (ub & 0xFFFF0000u);
}
__device__ inline float bf_lo(unsigned p) { return __uint_as_float(p << 16); }
__device__ inline float bf_hi(unsigned p) { return __uint_as_float(p & 0xFFFF0000u); }

// ------------------- embed gather + BN stats (layer 0, slot-spread) + degree hist
__global__ __launch_bounds__(256) void k_embed_hist(const int* __restrict__ idx,
                                                    const float* __restrict__ embed,
                                                    float* __restrict__ x,
                                                    float* __restrict__ stats, // [64][256]
                                                    const int* __restrict__ ei,
                                                    int* __restrict__ deg) {
    int tid = threadIdx.x;
    int e = blockIdx.x * 256 + tid;
    if (e < NE) atomicAdd(&deg[ei[NE + e]], 1);

    int i0 = blockIdx.x * 256 + tid;
    int stride = gridDim.x * 256;                 // 800000, multiple of 128
    float s = 0.f, q = 0.f;
    for (int i = i0; i < NN * HCC; i += stride) {
        float v = embed[idx[i >> 7] * HCC + (i & 127)];
        x[i] = v; s += v; q += v * v;
    }
    __shared__ float ssum[256], ssq[256];
    ssum[tid] = s; ssq[tid] = q;
    __syncthreads();
    int slot = blockIdx.x & (NSLOT - 1);
    if (tid < HCC) {
        atomicAdd(&stats[slot * 256 + tid],       ssum[tid] + ssum[tid + HCC]);
        atomicAdd(&stats[slot * 256 + HCC + tid], ssq[tid]  + ssq[tid + HCC]);
    }
}

// ---- 3-phase multi-block exclusive scan of deg -> rowptr (rowptr NOT mutated later)
__global__ __launch_bounds__(256) void k_scan1(const int* __restrict__ deg,
                                               int* __restrict__ rowptr,
                                               int* __restrict__ part) {
    __shared__ int sh[256];
    int b = blockIdx.x, t = threadIdx.x;
    int base = b * 1024 + t * 4;
    int v0 = (base     < NN) ? deg[base]     : 0;
    int v1 = (base + 1 < NN) ? deg[base + 1] : 0;
    int v2 = (base + 2 < NN) ? deg[base + 2] : 0;
    int v3 = (base + 3 < NN) ? deg[base + 3] : 0;
    int s = v0 + v1 + v2 + v3;
    sh[t] = s;
    __syncthreads();
#pragma unroll
    for (int off = 1; off < 256; off <<= 1) {
        int u = (t >= off) ? sh[t - off] : 0;
        __syncthreads();
        sh[t] += u;
        __syncthreads();
    }
    if (t == 255) part[b] = sh[255];
    int p = sh[t] - s;                            // exclusive prefix of this thread
    if (base     < NN) rowptr[base]     = p; p += v0;
    if (base + 1 < NN) rowptr[base + 1] = p; p += v1;
    if (base + 2 < NN) rowptr[base + 2] = p; p += v2;
    if (base + 3 < NN) rowptr[base + 3] = p;
}

__global__ void k_scan2(int* __restrict__ part, int* __restrict__ rowptr) {
    if (threadIdx.x == 0) {
        int run = 0;
        for (int i = 0; i < SCB; i++) { int v = part[i]; part[i] = run; run += v; }
        rowptr[NN] = run;                         // == NE
    }
}

// phase 3: add block offsets; also init per-bucket tail counters from rowptr
__global__ __launch_bounds__(256) void k_scan3(int* __restrict__ rowptr,
                                               const int* __restrict__ part,
                                               int* __restrict__ bcnt) {
    int b = blockIdx.x, t = threadIdx.x;
    int off = part[b];
    int base = b * 1024 + t * 4;
#pragma unroll
    for (int k = 0; k < 4; k++) {
        int ix = base + k;
        if (ix < NN) {
            int v = rowptr[ix] + off;
            rowptr[ix] = v;
            if ((ix & 127) == 0) bcnt[ix >> 7] = v;
        }
    }
}

// -------- CSR build phase A: LDS-aggregated bucket binning.
__global__ __launch_bounds__(256) void k_bin(const int* __restrict__ ei,
                                             int* __restrict__ bcnt,
                                             unsigned* __restrict__ e_src) {
    __shared__ int hist[NBUK], base[NBUK];
    int b = blockIdx.x, t = threadIdx.x;
    int e0 = b * EB;
    int nE = min(EB, NE - e0);

    for (int i = t; i < NBUK; i += 256) hist[i] = 0;
    __syncthreads();
    for (int i = t; i < nE; i += 256)
        atomicAdd(&hist[ei[NE + e0 + i] >> 7], 1);
    __syncthreads();
    for (int i = t; i < NBUK; i += 256) {
        int c = hist[i];
        if (c) base[i] = atomicAdd(&bcnt[i], c);
        hist[i] = 0;                              // reuse as placement offset
    }
    __syncthreads();
    for (int i = t; i < nE; i += 256) {
        int e = e0 + i;
        int d = ei[NE + e];
        int s = ei[e];
        int bk = d >> 7;
        int pos = base[bk] + atomicAdd(&hist[bk], 1);
        e_src[pos] = (unsigned)s | ((unsigned)(d & 127) << 17);
    }
}

// -------- CSR build phase B: within-bucket placement to exact CSR order.
__global__ __launch_bounds__(256) void k_place(const int* __restrict__ rowptr,
                                               unsigned* __restrict__ e_src) {
    __shared__ int lrp[129];
    __shared__ int cnt[128];
    int b = blockIdx.x, t = threadIdx.x;
    int d0 = b * 128;
    if (t < 128) {
        int ix = d0 + t;
        lrp[t] = (ix <= NN) ? rowptr[ix] : NE;
        cnt[t] = 0;
    }
    if (t == 0) lrp[128] = rowptr[min(d0 + 128, NN)];
    __syncthreads();
    int rS = lrp[0], rE = lrp[128];
    int n = rE - rS;
    unsigned pk[14];
#pragma unroll
    for (int k = 0; k < 14; k++) {
        int i = t + k * 256;
        if (i < n) pk[k] = e_src[rS + i];
    }
    __syncthreads();                              // all reads done before any write
#pragma unroll
    for (int k = 0; k < 14; k++) {
        int i = t + k * 256;
        if (i < n) {
            unsigned p = pk[k];
            int dl = p >> 17;
            int pos = lrp[dl] + atomicAdd(&cnt[dl], 1);
            e_src[pos] = p & 0x1FFFFu;
        }
    }
}

// ---------- fused BNfin(64-slot) + BN-apply + Linear+ReLU + GATw + att dots
// v4: 512 threads, 128 nodes/block. role = wv&3 (j-/k-slice, head),
// half = wv>>2 (64-node half). w1/w2 share one LDS buffer (w2 via registers).
__global__ __launch_bounds__(512) void k_fused(const float* __restrict__ x,
                                               const float* __restrict__ stats, // [64][256]
                                               const float* __restrict__ gamma,
                                               const float* __restrict__ beta,
                                               const float* __restrict__ W1, // [32,128]
                                               const float* __restrict__ b1, // [32]
                                               const float* __restrict__ W2, // [128,32]
                                               const float* __restrict__ aS, // [4,32]
                                               const float* __restrict__ aD, // [4,32]
                                               unsigned* __restrict__ h,     // [N,64] packed
                                               float* __restrict__ asrc,     // [N,4]
                                               float* __restrict__ adst) {   // [N,4]
    __shared__ unsigned xb2[FB * X2S];            // 34304 B
    __shared__ float yt[FB * YS];                 // 16896 B
    __shared__ float wbuf[4096];                  // 16384 B (w1, then w2)
    __shared__ float attS[128], attD[128], ssl[256];  // 2048 B
    int tid = threadIdx.x;
    int node0 = blockIdx.x * FB;
    int nNodes = min(FB, NN - node0);

    // prefetch w2 into registers; stage w1 into wbuf
    float4 w2r[2];
#pragma unroll
    for (int k = 0; k < 2; k++) w2r[k] = ((const float4*)W2)[tid + 512 * k];
#pragma unroll
    for (int k = 0; k < 2; k++) ((float4*)wbuf)[tid + 512 * k] = ((const float4*)W1)[tid + 512 * k];
    if (tid < 128) {
        attS[tid] = aS[tid]; attD[tid] = aD[tid];
        float s = 0.f, q = 0.f;
        for (int sl = 0; sl < NSLOT; sl++) {
            s += stats[sl * 256 + tid];
            q += stats[sl * 256 + HCC + tid];
        }
        float mean = s * (1.0f / NN);
        float var  = q * (1.0f / NN) - mean * mean;
        float sc   = gamma[tid] * rsqrtf(var + BN_EPS);
        ssl[tid]       = sc;
        ssl[HCC + tid] = beta[tid] - mean * sc;
    }
    __syncthreads();   // ssl read cross-wave below

    // stage x tile: BN-apply then pack to bf16 pairs
    {
        int cS = (tid * 4) & 127;
        float4 scv = *(const float4*)&ssl[cS];
        float4 shv = *(const float4*)&ssl[HCC + cS];
        for (int f4 = tid; f4 < nNodes * 32; f4 += 512) {
            int f = f4 * 4; int n = f >> 7; int c = f & 127;
            float4 xv = *(const float4*)(x + (size_t)(node0 + n) * HCC + c);
            float v0 = xv.x * scv.x + shv.x;
            float v1 = xv.y * scv.y + shv.y;
            float v2 = xv.z * scv.z + shv.z;
            float v3 = xv.w * scv.w + shv.w;
            unsigned* dst = &xb2[n * X2S + (c >> 1)];
            dst[0] = f2bf_pack(v0, v1);
            dst[1] = f2bf_pack(v2, v3);
        }
    }
    __syncthreads();

    int lane = tid & 63, wv = tid >> 6;           // wv in [0,8)
    int role = wv & 3, half = wv >> 2;
    int n = half * 64 + lane;

    // ---- stage 1: y[n][j0..j0+7] (wbuf holds w1)
    {
        int j0 = role * 8;
        float acc[8];
#pragma unroll
        for (int k = 0; k < 8; k++) acc[k] = b1[j0 + k];
        if (n < nNodes) {
            for (int cb = 0; cb < 128; cb += 4) {
                unsigned p0 = xb2[n * X2S + (cb >> 1)];
                unsigned p1 = xb2[n * X2S + (cb >> 1) + 1];
                float xv0 = bf_lo(p0), xv1 = bf_hi(p0);
                float xv2 = bf_lo(p1), xv3 = bf_hi(p1);
#pragma unroll
                for (int k = 0; k < 8; k++) {
                    float4 w = *(const float4*)&wbuf[(j0 + k) * 128 + cb];
                    acc[k] += xv0 * w.x + xv1 * w.y + xv2 * w.z + xv3 * w.w;
                }
            }
#pragma unroll
            for (int k = 0; k < 8; k++) yt[n * YS + j0 + k] = fmaxf(acc[k], 0.f);
        }
    }
    __syncthreads();   // all waves done with wbuf(w1) and yt writes

    // swap: wbuf <- w2 (from registers)
#pragma unroll
    for (int k = 0; k < 2; k++) ((float4*)wbuf)[tid + 512 * k] = w2r[k];
    __syncthreads();

    // ---- stage 2: h[n][k0..k0+31] (bf16), head hd = role (wbuf holds w2)
    if (n < nNodes) {
        int k0 = role * 32, hd = role;
        float yreg[32];
#pragma unroll
        for (int j = 0; j < 32; j++) yreg[j] = yt[n * YS + j];
        float sa = 0.f, da = 0.f;
        unsigned* hrow = h + (size_t)(node0 + n) * 64;
        for (int kb = 0; kb < 32; kb += 8) {
            float acck[8];
#pragma unroll
            for (int kk = 0; kk < 8; kk++) acck[kk] = 0.f;
#pragma unroll
            for (int j = 0; j < 32; j += 4) {
#pragma unroll
                for (int kk = 0; kk < 8; kk++) {
                    float4 w = *(const float4*)&wbuf[(k0 + kb + kk) * 32 + j];
                    acck[kk] += yreg[j] * w.x + yreg[j + 1] * w.y +
                                yreg[j + 2] * w.z + yreg[j + 3] * w.w;
                }
            }
#pragma unroll
            for (int kk = 0; kk < 8; kk++) {
                sa += acck[kk] * attS[hd * 32 + kb + kk];
                da += acck[kk] * attD[hd * 32 + kb + kk];
            }
            uint4 pk;
            pk.x = f2bf_pack(acck[0], acck[1]);
            pk.y = f2bf_pack(acck[2], acck[3]);
            pk.z = f2bf_pack(acck[4], acck[5]);
            pk.w = f2bf_pack(acck[6], acck[7]);
            *(uint4*)(hrow + ((k0 + kb) >> 1)) = pk;
        }
        asrc[(node0 + n) * 4 + hd] = sa;
        adst[(node0 + n) * 4 + hd] = da;
    }
}

// -------- gather-aggregate v5 (lean epilogue, no spill):
// one 16-lane group per dst node; 4 independent nodes per wave.
__global__ __launch_bounds__(256) void k_agg(const int* __restrict__ rowptr,
                                             const int* __restrict__ e_src,
                                             const float* __restrict__ asrc,
                                             const float* __restrict__ adst,
                                             const unsigned* __restrict__ h, // [N,64]
                                             const float* __restrict__ gat_b,
                                             float* __restrict__ xo,
                                             float* __restrict__ stats,      // [64][256]
                                             int do_stats) {
    int tid = threadIdx.x, lane = tid & 63, wv = tid >> 6;
    int g  = lane >> 4;        // node group 0..3
    int li = lane & 15;        // lane within group: channels 8li..8li+7
    int hd = li >> 2;          // head of this channel block
    int d  = blockIdx.x * 16 + wv * 4 + g;     // grid is exactly NN/16

    float4 bA = *(const float4*)(gat_b + li * 8);
    float4 bB = *(const float4*)(gat_b + li * 8 + 4);

    int begin = rowptr[d];
    int end   = rowptr[d + 1];
    float adv = adst[d * 4 + hd];
    float asl = asrc[d * 4 + hd];
    uint4 hs  = *(const uint4*)(h + (size_t)d * 64 + li * 4);

    float acc[8];
#pragma unroll
    for (int k = 0; k < 8; k++) acc[k] = 0.f;
    float ws = 0.f;

    int s[4];
    if (begin < end) {
#pragma unroll
        for (int t = 0; t < 4; t++) s[t] = e_src[min(begin + t, end - 1)];
    }

    for (int j = begin; j < end; j += 4) {
        uint4 hv[4];
#pragma unroll
        for (int t = 0; t < 4; t++) hv[t] = *(const uint4*)(h + (size_t)s[t] * 64 + li * 4);
        float av[4];
#pragma unroll
        for (int t = 0; t < 4; t++) av[t] = asrc[s[t] * 4 + hd];
        // prefetch next indices (independent of current gathers)
        int jn = j + 4;
        int sn[4];
#pragma unroll
        for (int t = 0; t < 4; t++) sn[t] = s[t];
        if (jn < end) {
#pragma unroll
            for (int t = 0; t < 4; t++) sn[t] = e_src[min(jn + t, end - 1)];
        }
        float w[4];
#pragma unroll
        for (int t = 0; t < 4; t++) {
            float l = av[t] + adv; l = l > 0.f ? l : 0.2f * l;
            w[t] = (j + t < end) ? __expf(l) : 0.f;
        }
#pragma unroll
        for (int t = 0; t < 4; t++) {
            acc[0] += w[t] * bf_lo(hv[t].x); acc[1] += w[t] * bf_hi(hv[t].x);
            acc[2] += w[t] * bf_lo(hv[t].y); acc[3] += w[t] * bf_hi(hv[t].y);
            acc[4] += w[t] * bf_lo(hv[t].z); acc[5] += w[t] * bf_hi(hv[t].z);
            acc[6] += w[t] * bf_lo(hv[t].w); acc[7] += w[t] * bf_hi(hv[t].w);
            ws += w[t];
        }
#pragma unroll
        for (int t = 0; t < 4; t++) s[t] = sn[t];
    }

    // self loop
    {
        float l = asl + adv; l = l > 0.f ? l : 0.2f * l;
        float w = __expf(l);
        acc[0] += w * bf_lo(hs.x); acc[1] += w * bf_hi(hs.x);
        acc[2] += w * bf_lo(hs.y); acc[3] += w * bf_hi(hs.y);
        acc[4] += w * bf_lo(hs.z); acc[5] += w * bf_hi(hs.z);
        acc[6] += w * bf_lo(hs.w); acc[7] += w * bf_hi(hs.w);
        ws += w;
    }

    float inv = 1.0f / (ws + 1e-16f);
    float o[8];
    o[0] = acc[0] * inv + bA.x; o[1] = acc[1] * inv + bA.y;
    o[2] = acc[2] * inv + bA.z; o[3] = acc[3] * inv + bA.w;
    o[4] = acc[4] * inv + bB.x; o[5] = acc[5] * inv + bB.y;
    o[6] = acc[6] * inv + bB.z; o[7] = acc[7] * inv + bB.w;
    float* orow = xo + (size_t)d * HCC + li * 8;
    *(float4*)orow       = make_float4(o[0], o[1], o[2], o[3]);
    *(float4*)(orow + 4) = make_float4(o[4], o[5], o[6], o[7]);

    if (!do_stats) return;
    __shared__ float redS[16 * 128], redQ[16 * 128];
    int r = wv * 4 + g;
#pragma unroll
    for (int k = 0; k < 8; k++) {
        redS[r * 128 + li * 8 + k] = o[k];
        redQ[r * 128 + li * 8 + k] = o[k] * o[k];
    }
    __syncthreads();
    int slot = blockIdx.x & (NSLOT - 1);
    if (tid < 128) {
        float v = 0.f;
#pragma unroll
        for (int rr = 0; rr < 16; rr++) v += redS[rr * 128 + tid];
        atomicAdd(&stats[slot * 256 + tid], v);
    } else {
        int c = tid - 128;
        float v = 0.f;
#pragma unroll
        for (int rr = 0; rr < 16; rr++) v += redQ[rr * 128 + c];
        atomicAdd(&stats[slot * 256 + HCC + c], v);
    }
}

// ------------- readout phase A: per-graph channel sums
__global__ __launch_bounds__(256) void k_pool(const float* __restrict__ x,
                                              const int* __restrict__ batch,
                                              float* __restrict__ gsum,  // [G,128]
                                              float* __restrict__ gcnt) {// [G]
    int nb = blockIdx.x * 64, t = threadIdx.x;
    int c = t & 127, half = t >> 7;
    float s = 0.f, cnt = 0.f;
    int curg = -1;
    for (int k = half; k < 64; k += 2) {
        int n = nb + k;
        if (n >= NN) break;
        int g = batch[n];
        if (g != curg) {
            if (curg >= 0) {
                atomicAdd(&gsum[curg * HCC + c], s);
                if (c == 0) atomicAdd(&gcnt[curg], cnt);
            }
            curg = g; s = 0.f; cnt = 0.f;
        }
        s += x[(size_t)n * HCC + c];
        cnt += 1.f;
    }
    if (curg >= 0) {
        atomicAdd(&gsum[curg * HCC + c], s);
        if (c == 0) atomicAdd(&gcnt[curg], cnt);
    }
}

// ------------- readout phase B: out[g] = W·gsum[g] + cnt[g]·b  (tiny GEMV)
__global__ __launch_bounds__(128) void k_out(const float* __restrict__ gsum,
                                             const float* __restrict__ gcnt,
                                             const float* __restrict__ W,  // [10,128]
                                             const float* __restrict__ bb, // [10]
                                             float* __restrict__ out) {    // [G,10]
    __shared__ float v[128];
    int g = blockIdx.x, t = threadIdx.x;
    v[t] = gsum[g * HCC + t];
    __syncthreads();
    if (t < NOUT) {
        float acc = gcnt[g] * bb[t];
        const float* wr = W + t * HCC;
        for (int c = 0; c < HCC; c++) acc += v[c] * wr[c];
        out[g * NOUT + t] = acc;
    }
}

extern "C" void kernel_launch(void* const* d_in, const int* in_sizes, int n_in,
                              void* d_out, int out_size, void* d_ws, size_t ws_size,
                              hipStream_t stream) {
    const int*   x_idx = (const int*)d_in[0];
    const int*   ei    = (const int*)d_in[1];
    const int*   batch = (const int*)d_in[2];
    const float* embed = (const float*)d_in[3];
    const float* bn_g  = (const float*)d_in[4];
    const float* bn_b  = (const float*)d_in[5];
    const float* lin_W = (const float*)d_in[6];
    const float* lin_b = (const float*)d_in[7];
    const float* gat_W = (const float*)d_in[8];
    const float* att_s = (const float*)d_in[9];
    const float* att_d = (const float*)d_in[10];
    const float* gat_b = (const float*)d_in[11];
    const float* ro_W  = (const float*)d_in[12];
    const float* ro_b  = (const float*)d_in[13];
    float* out = (float*)d_out;

    // workspace layout (stats | gsum | gcnt | deg contiguous -> single memset)
    const size_t STG = (size_t)NSLOT * 256;                // floats per stats stage
    float*    x     = (float*)d_ws;                        // [N,128] fp32
    unsigned* h     = (unsigned*)(x + (size_t)NN * HCC);   // [N,64] packed bf16
    float*    asrc  = (float*)(h + (size_t)NN * 64);       // [N,4]
    float*    adst  = asrc + (size_t)NN * NHD;             // [N,4]
    float*    stats = adst + (size_t)NN * NHD;             // [3][64][256]
    float*    gsum  = stats + 3 * STG;                     // [G,128]
    float*    gcnt  = gsum + (size_t)NG * HCC;             // [G]
    int*      deg    = (int*)(gcnt + NG);                  // [N]
    int*      rowptr = deg + NN;                           // [N+1]
    unsigned* e_src  = (unsigned*)(rowptr + NN + 1);       // [E]
    int*      bcnt   = (int*)(e_src + NE);                 // [NBUK]
    int*      part   = bcnt + NBUK;                        // [49]

    hipMemsetAsync(stats, 0,
                   (3 * STG + (size_t)NG * HCC + NG) * sizeof(float) + NN * sizeof(int),
                   stream);

    k_embed_hist<<<(NE + 255) / 256, 256, 0, stream>>>(x_idx, embed, x, stats, ei, deg);
    k_scan1<<<SCB, 256, 0, stream>>>(deg, rowptr, part);
    k_scan2<<<1, 64, 0, stream>>>(part, rowptr);
    k_scan3<<<SCB, 256, 0, stream>>>(rowptr, part, bcnt);
    k_bin<<<(NE + EB - 1) / EB, 256, 0, stream>>>(ei, bcnt, e_src);
    k_place<<<NBUK, 256, 0, stream>>>(rowptr, e_src);

    for (int l = 0; l < NL; ++l) {
        k_fused<<<(NN + FB - 1) / FB, 512, 0, stream>>>(x, stats + l * STG,
                                                    bn_g + l * HCC, bn_b + l * HCC,
                                                    lin_W + l * CC * HCC, lin_b + l * CC,
                                                    gat_W + l * HCC * CC,
                                                    att_s + l * NHD * CC,
                                                    att_d + l * NHD * CC,
                                                    h, asrc, adst);
        k_agg<<<NN / 16, 256, 0, stream>>>(rowptr, (const int*)e_src, asrc, adst, h,
                                           gat_b + l * HCC, x,
                                           stats + (l + 1) * STG,
                                           (l < NL - 1) ? 1 : 0);
    }

    k_pool<<<(NN + 63) / 64, 256, 0, stream>>>(x, batch, gsum, gcnt);
    k_out<<<NG, 128, 0, stream>>>(gsum, gcnt, ro_W, ro_b, out);
}

// Round 19
// 390.650 us; speedup vs baseline: 1.0890x; 1.0890x over previous
//
#include <hip/hip_runtime.h>

// Problem constants (match reference)
constexpr int NN   = 50000;          // nodes
constexpr int NE   = 800000;         // edges before self loops
constexpr int NHD  = 4;              // heads
constexpr int CC   = 32;             // channels per head
constexpr int HCC  = 128;            // NHD*CC
constexpr int NL   = 3;              // layers
constexpr int NG   = 128;            // graphs
constexpr int NOUT = 10;             // out channels
constexpr float BN_EPS = 1e-5f;

constexpr int X2S = 67;              // LDS x-row stride in packed uints (bank-safe)
constexpr int YS = 33;               // LDS y-row stride
constexpr int NSLOT = 64;            // stats slots (atomic-contention spreading)
constexpr int SCB = (NN + 1023) / 1024;   // 49 scan blocks
constexpr int NBUK = (NN + 127) / 128;    // 391 dst buckets (128 dsts each)
constexpr int EB  = 8192;            // edges per k_bin block

// fp32 -> bf16 (round-to-nearest-even), packed pair helpers
__device__ inline unsigned f2bf_pack(float a, float b) {
    unsigned ua = __float_as_uint(a); ua += 0x7FFFu + ((ua >> 16) & 1u);
    unsigned ub = __float_as_uint(b); ub += 0x7FFFu + ((ub >> 16) & 1u);
    return (ua >> 16) | (ub & 0xFFFF0000u);
}
__device__ inline float bf_lo(unsigned p) { return __uint_as_float(p << 16); }
__device__ inline float bf_hi(unsigned p) { return __uint_as_float(p & 0xFFFF0000u); }

// ------------------- embed gather + BN stats (layer 0, slot-spread) + degree hist
__global__ __launch_bounds__(256) void k_embed_hist(const int* __restrict__ idx,
                                                    const float* __restrict__ embed,
                                                    float* __restrict__ x,
                                                    float* __restrict__ stats, // [64][256]
                                                    const int* __restrict__ ei,
                                                    int* __restrict__ deg) {
    int tid = threadIdx.x;
    int e = blockIdx.x * 256 + tid;
    if (e < NE) atomicAdd(&deg[ei[NE + e]], 1);

    int i0 = blockIdx.x * 256 + tid;
    int stride = gridDim.x * 256;                 // 800000, multiple of 128
    float s = 0.f, q = 0.f;
    for (int i = i0; i < NN * HCC; i += stride) {
        float v = embed[idx[i >> 7] * HCC + (i & 127)];
        x[i] = v; s += v; q += v * v;
    }
    __shared__ float ssum[256], ssq[256];
    ssum[tid] = s; ssq[tid] = q;
    __syncthreads();
    int slot = blockIdx.x & (NSLOT - 1);
    if (tid < HCC) {
        atomicAdd(&stats[slot * 256 + tid],       ssum[tid] + ssum[tid + HCC]);
        atomicAdd(&stats[slot * 256 + HCC + tid], ssq[tid]  + ssq[tid + HCC]);
    }
}

// ---- 3-phase multi-block exclusive scan of deg -> rowptr (rowptr NOT mutated later)
__global__ __launch_bounds__(256) void k_scan1(const int* __restrict__ deg,
                                               int* __restrict__ rowptr,
                                               int* __restrict__ part) {
    __shared__ int sh[256];
    int b = blockIdx.x, t = threadIdx.x;
    int base = b * 1024 + t * 4;
    int v0 = (base     < NN) ? deg[base]     : 0;
    int v1 = (base + 1 < NN) ? deg[base + 1] : 0;
    int v2 = (base + 2 < NN) ? deg[base + 2] : 0;
    int v3 = (base + 3 < NN) ? deg[base + 3] : 0;
    int s = v0 + v1 + v2 + v3;
    sh[t] = s;
    __syncthreads();
#pragma unroll
    for (int off = 1; off < 256; off <<= 1) {
        int u = (t >= off) ? sh[t - off] : 0;
        __syncthreads();
        sh[t] += u;
        __syncthreads();
    }
    if (t == 255) part[b] = sh[255];
    int p = sh[t] - s;                            // exclusive prefix of this thread
    if (base     < NN) rowptr[base]     = p; p += v0;
    if (base + 1 < NN) rowptr[base + 1] = p; p += v1;
    if (base + 2 < NN) rowptr[base + 2] = p; p += v2;
    if (base + 3 < NN) rowptr[base + 3] = p;
}

__global__ void k_scan2(int* __restrict__ part, int* __restrict__ rowptr) {
    if (threadIdx.x == 0) {
        int run = 0;
        for (int i = 0; i < SCB; i++) { int v = part[i]; part[i] = run; run += v; }
        rowptr[NN] = run;                         // == NE
    }
}

// phase 3: add block offsets; also init per-bucket tail counters from rowptr
__global__ __launch_bounds__(256) void k_scan3(int* __restrict__ rowptr,
                                               const int* __restrict__ part,
                                               int* __restrict__ bcnt) {
    int b = blockIdx.x, t = threadIdx.x;
    int off = part[b];
    int base = b * 1024 + t * 4;
#pragma unroll
    for (int k = 0; k < 4; k++) {
        int ix = base + k;
        if (ix < NN) {
            int v = rowptr[ix] + off;
            rowptr[ix] = v;
            if ((ix & 127) == 0) bcnt[ix >> 7] = v;
        }
    }
}

// -------- CSR build phase A: LDS-aggregated bucket binning.
__global__ __launch_bounds__(256) void k_bin(const int* __restrict__ ei,
                                             int* __restrict__ bcnt,
                                             unsigned* __restrict__ e_src) {
    __shared__ int hist[NBUK], base[NBUK];
    int b = blockIdx.x, t = threadIdx.x;
    int e0 = b * EB;
    int nE = min(EB, NE - e0);

    for (int i = t; i < NBUK; i += 256) hist[i] = 0;
    __syncthreads();
    for (int i = t; i < nE; i += 256)
        atomicAdd(&hist[ei[NE + e0 + i] >> 7], 1);
    __syncthreads();
    for (int i = t; i < NBUK; i += 256) {
        int c = hist[i];
        if (c) base[i] = atomicAdd(&bcnt[i], c);
        hist[i] = 0;                              // reuse as placement offset
    }
    __syncthreads();
    for (int i = t; i < nE; i += 256) {
        int e = e0 + i;
        int d = ei[NE + e];
        int s = ei[e];
        int bk = d >> 7;
        int pos = base[bk] + atomicAdd(&hist[bk], 1);
        e_src[pos] = (unsigned)s | ((unsigned)(d & 127) << 17);
    }
}

// -------- CSR build phase B: within-bucket placement to exact CSR order.
__global__ __launch_bounds__(256) void k_place(const int* __restrict__ rowptr,
                                               unsigned* __restrict__ e_src) {
    __shared__ int lrp[129];
    __shared__ int cnt[128];
    int b = blockIdx.x, t = threadIdx.x;
    int d0 = b * 128;
    if (t < 128) {
        int ix = d0 + t;
        lrp[t] = (ix <= NN) ? rowptr[ix] : NE;
        cnt[t] = 0;
    }
    if (t == 0) lrp[128] = rowptr[min(d0 + 128, NN)];
    __syncthreads();
    int rS = lrp[0], rE = lrp[128];
    int n = rE - rS;
    unsigned pk[14];
#pragma unroll
    for (int k = 0; k < 14; k++) {
        int i = t + k * 256;
        if (i < n) pk[k] = e_src[rS + i];
    }
    __syncthreads();                              // all reads done before any write
#pragma unroll
    for (int k = 0; k < 14; k++) {
        int i = t + k * 256;
        if (i < n) {
            unsigned p = pk[k];
            int dl = p >> 17;
            int pos = lrp[dl] + atomicAdd(&cnt[dl], 1);
            e_src[pos] = p & 0x1FFFFu;
        }
    }
}

// ---------- fused BNfin(64-slot) + BN-apply + Linear+ReLU + GATw + att dots
// v5: NO LDS weight buffer — wave-uniform weight indices forced scalar via
// readfirstlane; W1/W2/b1/aS/aD read directly from global -> s_load (SMEM
// pipe), freeing the LDS pipe (R18 diagnosis: ~512 ds_read_b128/wave of
// uniform weight reads were the per-CU shared-resource bound). LDS 27.6 KB.
__global__ __launch_bounds__(256) void k_fused(const float* __restrict__ x,
                                               const float* __restrict__ stats, // [64][256]
                                               const float* __restrict__ gamma,
                                               const float* __restrict__ beta,
                                               const float* __restrict__ W1, // [32,128]
                                               const float* __restrict__ b1, // [32]
                                               const float* __restrict__ W2, // [128,32]
                                               const float* __restrict__ aS, // [4,32]
                                               const float* __restrict__ aD, // [4,32]
                                               unsigned* __restrict__ h,     // [N,64] packed
                                               float* __restrict__ asrc,     // [N,4]
                                               float* __restrict__ adst) {   // [N,4]
    __shared__ unsigned xb2[64 * X2S];            // 17152 B
    __shared__ float yt[64 * YS];                 //  8448 B
    __shared__ float ssl[256];                    //  1024 B
    int tid = threadIdx.x;
    int node0 = blockIdx.x * 64;
    int nNodes = min(64, NN - node0);

    if (tid < 128) {
        float s = 0.f, q = 0.f;
        for (int sl = 0; sl < NSLOT; sl++) {
            s += stats[sl * 256 + tid];
            q += stats[sl * 256 + HCC + tid];
        }
        float mean = s * (1.0f / NN);
        float var  = q * (1.0f / NN) - mean * mean;
        float sc   = gamma[tid] * rsqrtf(var + BN_EPS);
        ssl[tid]       = sc;
        ssl[HCC + tid] = beta[tid] - mean * sc;
    }
    __syncthreads();   // ssl read cross-wave below

    // stage x tile: BN-apply then pack to bf16 pairs
    {
        int cS = (tid * 4) & 127;
        float4 scv = *(const float4*)&ssl[cS];
        float4 shv = *(const float4*)&ssl[HCC + cS];
        for (int f4 = tid; f4 < nNodes * 32; f4 += 256) {
            int f = f4 * 4; int n = f >> 7; int c = f & 127;
            float4 xv = *(const float4*)(x + (size_t)(node0 + n) * HCC + c);
            float v0 = xv.x * scv.x + shv.x;
            float v1 = xv.y * scv.y + shv.y;
            float v2 = xv.z * scv.z + shv.z;
            float v3 = xv.w * scv.w + shv.w;
            unsigned* dst = &xb2[n * X2S + (c >> 1)];
            dst[0] = f2bf_pack(v0, v1);
            dst[1] = f2bf_pack(v2, v3);
        }
    }
    __syncthreads();

    int lane = tid & 63;
    // wave index forced into an SGPR: all derived weight indices are provably
    // wave-uniform -> compiler emits s_load for W1/W2/b1/aS/aD accesses.
    int wv = __builtin_amdgcn_readfirstlane(tid >> 6);
    int n = lane;

    // ---- stage 1: y[n][j0..j0+7] (weights via scalar loads)
    {
        int j0 = wv * 8;
        const float* w1p = W1 + j0 * 128;
        float acc[8];
#pragma unroll
        for (int k = 0; k < 8; k++) acc[k] = b1[j0 + k];
        if (n < nNodes) {
            for (int cb = 0; cb < 128; cb += 4) {
                unsigned p0 = xb2[n * X2S + (cb >> 1)];
                unsigned p1 = xb2[n * X2S + (cb >> 1) + 1];
                float xv0 = bf_lo(p0), xv1 = bf_hi(p0);
                float xv2 = bf_lo(p1), xv3 = bf_hi(p1);
#pragma unroll
                for (int k = 0; k < 8; k++) {
                    float4 w = *(const float4*)&w1p[k * 128 + cb];
                    acc[k] += xv0 * w.x + xv1 * w.y + xv2 * w.z + xv3 * w.w;
                }
            }
#pragma unroll
            for (int k = 0; k < 8; k++) yt[n * YS + j0 + k] = fmaxf(acc[k], 0.f);
        }
    }
    __syncthreads();

    // ---- stage 2: h[n][k0..k0+31] (bf16), head hd = wv (weights via s_load)
    if (n < nNodes) {
        int k0 = wv * 32, hd = wv;
        const float* w2p = W2 + k0 * 32;
        const float* aSp = aS + hd * 32;
        const float* aDp = aD + hd * 32;
        float yreg[32];
#pragma unroll
        for (int j = 0; j < 32; j++) yreg[j] = yt[n * YS + j];
        float sa = 0.f, da = 0.f;
        unsigned* hrow = h + (size_t)(node0 + n) * 64;
        for (int kb = 0; kb < 32; kb += 8) {
            float acck[8];
#pragma unroll
            for (int kk = 0; kk < 8; kk++) acck[kk] = 0.f;
#pragma unroll
            for (int j = 0; j < 32; j += 4) {
#pragma unroll
                for (int kk = 0; kk < 8; kk++) {
                    float4 w = *(const float4*)&w2p[(kb + kk) * 32 + j];
                    acck[kk] += yreg[j] * w.x + yreg[j + 1] * w.y +
                                yreg[j + 2] * w.z + yreg[j + 3] * w.w;
                }
            }
#pragma unroll
            for (int kk = 0; kk < 8; kk++) {
                sa += acck[kk] * aSp[kb + kk];
                da += acck[kk] * aDp[kb + kk];
            }
            uint4 pk;
            pk.x = f2bf_pack(acck[0], acck[1]);
            pk.y = f2bf_pack(acck[2], acck[3]);
            pk.z = f2bf_pack(acck[4], acck[5]);
            pk.w = f2bf_pack(acck[6], acck[7]);
            *(uint4*)(hrow + ((kb) >> 1) + (k0 >> 1)) = pk;
        }
        asrc[(node0 + n) * 4 + hd] = sa;
        adst[(node0 + n) * 4 + hd] = da;
    }
}

// -------- gather-aggregate v5 (lean epilogue, no spill):
// one 16-lane group per dst node; 4 independent nodes per wave.
__global__ __launch_bounds__(256) void k_agg(const int* __restrict__ rowptr,
                                             const int* __restrict__ e_src,
                                             const float* __restrict__ asrc,
                                             const float* __restrict__ adst,
                                             const unsigned* __restrict__ h, // [N,64]
                                             const float* __restrict__ gat_b,
                                             float* __restrict__ xo,
                                             float* __restrict__ stats,      // [64][256]
                                             int do_stats) {
    int tid = threadIdx.x, lane = tid & 63, wv = tid >> 6;
    int g  = lane >> 4;        // node group 0..3
    int li = lane & 15;        // lane within group: channels 8li..8li+7
    int hd = li >> 2;          // head of this channel block
    int d  = blockIdx.x * 16 + wv * 4 + g;     // grid is exactly NN/16

    float4 bA = *(const float4*)(gat_b + li * 8);
    float4 bB = *(const float4*)(gat_b + li * 8 + 4);

    int begin = rowptr[d];
    int end   = rowptr[d + 1];
    float adv = adst[d * 4 + hd];
    float asl = asrc[d * 4 + hd];
    uint4 hs  = *(const uint4*)(h + (size_t)d * 64 + li * 4);

    float acc[8];
#pragma unroll
    for (int k = 0; k < 8; k++) acc[k] = 0.f;
    float ws = 0.f;

    int s[4];
    if (begin < end) {
#pragma unroll
        for (int t = 0; t < 4; t++) s[t] = e_src[min(begin + t, end - 1)];
    }

    for (int j = begin; j < end; j += 4) {
        uint4 hv[4];
#pragma unroll
        for (int t = 0; t < 4; t++) hv[t] = *(const uint4*)(h + (size_t)s[t] * 64 + li * 4);
        float av[4];
#pragma unroll
        for (int t = 0; t < 4; t++) av[t] = asrc[s[t] * 4 + hd];
        // prefetch next indices (independent of current gathers)
        int jn = j + 4;
        int sn[4];
#pragma unroll
        for (int t = 0; t < 4; t++) sn[t] = s[t];
        if (jn < end) {
#pragma unroll
            for (int t = 0; t < 4; t++) sn[t] = e_src[min(jn + t, end - 1)];
        }
        float w[4];
#pragma unroll
        for (int t = 0; t < 4; t++) {
            float l = av[t] + adv; l = l > 0.f ? l : 0.2f * l;
            w[t] = (j + t < end) ? __expf(l) : 0.f;
        }
#pragma unroll
        for (int t = 0; t < 4; t++) {
            acc[0] += w[t] * bf_lo(hv[t].x); acc[1] += w[t] * bf_hi(hv[t].x);
            acc[2] += w[t] * bf_lo(hv[t].y); acc[3] += w[t] * bf_hi(hv[t].y);
            acc[4] += w[t] * bf_lo(hv[t].z); acc[5] += w[t] * bf_hi(hv[t].z);
            acc[6] += w[t] * bf_lo(hv[t].w); acc[7] += w[t] * bf_hi(hv[t].w);
            ws += w[t];
        }
#pragma unroll
        for (int t = 0; t < 4; t++) s[t] = sn[t];
    }

    // self loop
    {
        float l = asl + adv; l = l > 0.f ? l : 0.2f * l;
        float w = __expf(l);
        acc[0] += w * bf_lo(hs.x); acc[1] += w * bf_hi(hs.x);
        acc[2] += w * bf_lo(hs.y); acc[3] += w * bf_hi(hs.y);
        acc[4] += w * bf_lo(hs.z); acc[5] += w * bf_hi(hs.z);
        acc[6] += w * bf_lo(hs.w); acc[7] += w * bf_hi(hs.w);
        ws += w;
    }

    float inv = 1.0f / (ws + 1e-16f);
    float o[8];
    o[0] = acc[0] * inv + bA.x; o[1] = acc[1] * inv + bA.y;
    o[2] = acc[2] * inv + bA.z; o[3] = acc[3] * inv + bA.w;
    o[4] = acc[4] * inv + bB.x; o[5] = acc[5] * inv + bB.y;
    o[6] = acc[6] * inv + bB.z; o[7] = acc[7] * inv + bB.w;
    float* orow = xo + (size_t)d * HCC + li * 8;
    *(float4*)orow       = make_float4(o[0], o[1], o[2], o[3]);
    *(float4*)(orow + 4) = make_float4(o[4], o[5], o[6], o[7]);

    if (!do_stats) return;
    __shared__ float redS[16 * 128], redQ[16 * 128];
    int r = wv * 4 + g;
#pragma unroll
    for (int k = 0; k < 8; k++) {
        redS[r * 128 + li * 8 + k] = o[k];
        redQ[r * 128 + li * 8 + k] = o[k] * o[k];
    }
    __syncthreads();
    int slot = blockIdx.x & (NSLOT - 1);
    if (tid < 128) {
        float v = 0.f;
#pragma unroll
        for (int rr = 0; rr < 16; rr++) v += redS[rr * 128 + tid];
        atomicAdd(&stats[slot * 256 + tid], v);
    } else {
        int c = tid - 128;
        float v = 0.f;
#pragma unroll
        for (int rr = 0; rr < 16; rr++) v += redQ[rr * 128 + c];
        atomicAdd(&stats[slot * 256 + HCC + c], v);
    }
}

// ------------- readout phase A: per-graph channel sums
__global__ __launch_bounds__(256) void k_pool(const float* __restrict__ x,
                                              const int* __restrict__ batch,
                                              float* __restrict__ gsum,  // [G,128]
                                              float* __restrict__ gcnt) {// [G]
    int nb = blockIdx.x * 64, t = threadIdx.x;
    int c = t & 127, half = t >> 7;
    float s = 0.f, cnt = 0.f;
    int curg = -1;
    for (int k = half; k < 64; k += 2) {
        int n = nb + k;
        if (n >= NN) break;
        int g = batch[n];
        if (g != curg) {
            if (curg >= 0) {
                atomicAdd(&gsum[curg * HCC + c], s);
                if (c == 0) atomicAdd(&gcnt[curg], cnt);
            }
            curg = g; s = 0.f; cnt = 0.f;
        }
        s += x[(size_t)n * HCC + c];
        cnt += 1.f;
    }
    if (curg >= 0) {
        atomicAdd(&gsum[curg * HCC + c], s);
        if (c == 0) atomicAdd(&gcnt[curg], cnt);
    }
}

// ------------- readout phase B: out[g] = W·gsum[g] + cnt[g]·b  (tiny GEMV)
__global__ __launch_bounds__(128) void k_out(const float* __restrict__ gsum,
                                             const float* __restrict__ gcnt,
                                             const float* __restrict__ W,  // [10,128]
                                             const float* __restrict__ bb, // [10]
                                             float* __restrict__ out) {    // [G,10]
    __shared__ float v[128];
    int g = blockIdx.x, t = threadIdx.x;
    v[t] = gsum[g * HCC + t];
    __syncthreads();
    if (t < NOUT) {
        float acc = gcnt[g] * bb[t];
        const float* wr = W + t * HCC;
        for (int c = 0; c < HCC; c++) acc += v[c] * wr[c];
        out[g * NOUT + t] = acc;
    }
}

extern "C" void kernel_launch(void* const* d_in, const int* in_sizes, int n_in,
                              void* d_out, int out_size, void* d_ws, size_t ws_size,
                              hipStream_t stream) {
    const int*   x_idx = (const int*)d_in[0];
    const int*   ei    = (const int*)d_in[1];
    const int*   batch = (const int*)d_in[2];
    const float* embed = (const float*)d_in[3];
    const float* bn_g  = (const float*)d_in[4];
    const float* bn_b  = (const float*)d_in[5];
    const float* lin_W = (const float*)d_in[6];
    const float* lin_b = (const float*)d_in[7];
    const float* gat_W = (const float*)d_in[8];
    const float* att_s = (const float*)d_in[9];
    const float* att_d = (const float*)d_in[10];
    const float* gat_b = (const float*)d_in[11];
    const float* ro_W  = (const float*)d_in[12];
    const float* ro_b  = (const float*)d_in[13];
    float* out = (float*)d_out;

    // workspace layout (stats | gsum | gcnt | deg contiguous -> single memset)
    const size_t STG = (size_t)NSLOT * 256;                // floats per stats stage
    float*    x     = (float*)d_ws;                        // [N,128] fp32
    unsigned* h     = (unsigned*)(x + (size_t)NN * HCC);   // [N,64] packed bf16
    float*    asrc  = (float*)(h + (size_t)NN * 64);       // [N,4]
    float*    adst  = asrc + (size_t)NN * NHD;             // [N,4]
    float*    stats = adst + (size_t)NN * NHD;             // [3][64][256]
    float*    gsum  = stats + 3 * STG;                     // [G,128]
    float*    gcnt  = gsum + (size_t)NG * HCC;             // [G]
    int*      deg    = (int*)(gcnt + NG);                  // [N]
    int*      rowptr = deg + NN;                           // [N+1]
    unsigned* e_src  = (unsigned*)(rowptr + NN + 1);       // [E]
    int*      bcnt   = (int*)(e_src + NE);                 // [NBUK]
    int*      part   = bcnt + NBUK;                        // [49]

    hipMemsetAsync(stats, 0,
                   (3 * STG + (size_t)NG * HCC + NG) * sizeof(float) + NN * sizeof(int),
                   stream);

    k_embed_hist<<<(NE + 255) / 256, 256, 0, stream>>>(x_idx, embed, x, stats, ei, deg);
    k_scan1<<<SCB, 256, 0, stream>>>(deg, rowptr, part);
    k_scan2<<<1, 64, 0, stream>>>(part, rowptr);
    k_scan3<<<SCB, 256, 0, stream>>>(rowptr, part, bcnt);
    k_bin<<<(NE + EB - 1) / EB, 256, 0, stream>>>(ei, bcnt, e_src);
    k_place<<<NBUK, 256, 0, stream>>>(rowptr, e_src);

    for (int l = 0; l < NL; ++l) {
        k_fused<<<(NN + 63) / 64, 256, 0, stream>>>(x, stats + l * STG,
                                                    bn_g + l * HCC, bn_b + l * HCC,
                                                    lin_W + l * CC * HCC, lin_b + l * CC,
                                                    gat_W + l * HCC * CC,
                                                    att_s + l * NHD * CC,
                                                    att_d + l * NHD * CC,
                                                    h, asrc, adst);
        k_agg<<<NN / 16, 256, 0, stream>>>(rowptr, (const int*)e_src, asrc, adst, h,
                                           gat_b + l * HCC, x,
                                           stats + (l + 1) * STG,
                                           (l < NL - 1) ? 1 : 0);
    }

    k_pool<<<(NN + 63) / 64, 256, 0, stream>>>(x, batch, gsum, gcnt);
    k_out<<<NG, 128, 0, stream>>>(gsum, gcnt, ro_W, ro_b, out);
}

// Round 20
// 373.177 us; speedup vs baseline: 1.1400x; 1.0468x over previous
//
#include <hip/hip_runtime.h>

// Problem constants (match reference)
constexpr int NN   = 50000;          // nodes
constexpr int NE   = 800000;         // edges before self loops
constexpr int NHD  = 4;              // heads
constexpr int CC   = 32;             // channels per head
constexpr int HCC  = 128;            // NHD*CC
constexpr int NL   = 3;              // layers
constexpr int NG   = 128;            // graphs
constexpr int NOUT = 10;             // out channels
constexpr float BN_EPS = 1e-5f;

constexpr int X2S = 67;              // LDS x-row stride in packed uints (bank-safe)
constexpr int YS = 33;               // LDS y-row stride
constexpr int NSLOT = 64;            // stats slots (atomic-contention spreading)
constexpr int NBUK = (NN + 127) / 128;    // 391 dst buckets (128 dsts each)
constexpr int EB  = 8192;            // edges per k_bhist/k_bin block

// fp32 -> bf16 (round-to-nearest-even), packed pair helpers
__device__ inline unsigned f2bf_pack(float a, float b) {
    unsigned ua = __float_as_uint(a); ua += 0x7FFFu + ((ua >> 16) & 1u);
    unsigned ub = __float_as_uint(b); ub += 0x7FFFu + ((ub >> 16) & 1u);
    return (ua >> 16) | (ub & 0xFFFF0000u);
}
__device__ inline float bf_lo(unsigned p) { return __uint_as_float(p << 16); }
__device__ inline float bf_hi(unsigned p) { return __uint_as_float(p & 0xFFFF0000u); }

// ------------------- embed gather + BN stats (layer 0, slot-spread)
__global__ __launch_bounds__(256) void k_embed_stats(const int* __restrict__ idx,
                                                     const float* __restrict__ embed,
                                                     float* __restrict__ x,
                                                     float* __restrict__ stats) { // [64][256]
    int tid = threadIdx.x;
    int i0 = blockIdx.x * 256 + tid;
    int stride = gridDim.x * 256;                 // multiple of 128
    float s = 0.f, q = 0.f;
    for (int i = i0; i < NN * HCC; i += stride) {
        float v = embed[idx[i >> 7] * HCC + (i & 127)];
        x[i] = v; s += v; q += v * v;
    }
    __shared__ float ssum[256], ssq[256];
    ssum[tid] = s; ssq[tid] = q;
    __syncthreads();
    int slot = blockIdx.x & (NSLOT - 1);
    if (tid < HCC) {
        atomicAdd(&stats[slot * 256 + tid],       ssum[tid] + ssum[tid + HCC]);
        atomicAdd(&stats[slot * 256 + HCC + tid], ssq[tid]  + ssq[tid + HCC]);
    }
}

// -------- CSR build 1: LDS-aggregated bucket histogram (391 counters)
__global__ __launch_bounds__(256) void k_bhist(const int* __restrict__ ei,
                                               int* __restrict__ bkcnt) {
    __shared__ int hist[NBUK];
    int b = blockIdx.x, t = threadIdx.x;
    int e0 = b * EB, nE = min(EB, NE - e0);
    for (int i = t; i < NBUK; i += 256) hist[i] = 0;
    __syncthreads();
    for (int i = t; i < nE; i += 256)
        atomicAdd(&hist[ei[NE + e0 + i] >> 7], 1);
    __syncthreads();
    for (int i = t; i < NBUK; i += 256)
        if (hist[i]) atomicAdd(&bkcnt[i], hist[i]);
}

// -------- CSR build 2: parallel exclusive scan of 391 bucket totals
__global__ __launch_bounds__(512) void k_bscan(const int* __restrict__ bkcnt,
                                               int* __restrict__ bbase,
                                               int* __restrict__ bcnt,
                                               int* __restrict__ rowptr) {
    __shared__ int sc[512];
    int t = threadIdx.x;
    int v = (t < NBUK) ? bkcnt[t] : 0;
    sc[t] = v;
    __syncthreads();
#pragma unroll
    for (int off = 1; off < 512; off <<= 1) {
        int u = (t >= off) ? sc[t - off] : 0;
        __syncthreads();
        sc[t] += u;
        __syncthreads();
    }
    if (t < NBUK) {
        int excl = sc[t] - v;
        bbase[t] = excl;
        bcnt[t]  = excl;                          // atomic tail counters for k_bin
    }
    if (t == 0) rowptr[NN] = NE;
}

// -------- CSR build 3: LDS-aggregated bucket binning (range-reserved).
__global__ __launch_bounds__(256) void k_bin(const int* __restrict__ ei,
                                             int* __restrict__ bcnt,
                                             unsigned* __restrict__ e_src) {
    __shared__ int hist[NBUK], base[NBUK];
    int b = blockIdx.x, t = threadIdx.x;
    int e0 = b * EB;
    int nE = min(EB, NE - e0);

    for (int i = t; i < NBUK; i += 256) hist[i] = 0;
    __syncthreads();
    for (int i = t; i < nE; i += 256)
        atomicAdd(&hist[ei[NE + e0 + i] >> 7], 1);
    __syncthreads();
    for (int i = t; i < NBUK; i += 256) {
        int c = hist[i];
        if (c) base[i] = atomicAdd(&bcnt[i], c);
        hist[i] = 0;                              // reuse as placement offset
    }
    __syncthreads();
    for (int i = t; i < nE; i += 256) {
        int e = e0 + i;
        int d = ei[NE + e];
        int s = ei[e];
        int bk = d >> 7;
        int pos = base[bk] + atomicAdd(&hist[bk], 1);
        e_src[pos] = (unsigned)s | ((unsigned)(d & 127) << 17);
    }
}

// -------- CSR build 4: within-bucket placement; derives per-node rowptr
// from a local histogram (replaces the old deg/k_scan1-3 path entirely).
__global__ __launch_bounds__(256) void k_place(const int* __restrict__ bbase,
                                               unsigned* __restrict__ e_src,
                                               int* __restrict__ rowptr) {
    __shared__ int lcnt[128], sc[128], lrp[128], cnt[128];
    int b = blockIdx.x, t = threadIdx.x;
    int d0 = b * 128;
    int rS = bbase[b];
    int rE = (b + 1 < NBUK) ? bbase[b + 1] : NE;
    int n = rE - rS;
    if (t < 128) { lcnt[t] = 0; cnt[t] = 0; }
    __syncthreads();
    unsigned pk[14];
#pragma unroll
    for (int k = 0; k < 14; k++) {
        int i = t + k * 256;
        if (i < n) {
            pk[k] = e_src[rS + i];
            atomicAdd(&lcnt[pk[k] >> 17], 1);
        }
    }
    __syncthreads();
    // exclusive scan of the 128 local degrees
    if (t < 128) sc[t] = lcnt[t];
    __syncthreads();
#pragma unroll
    for (int off = 1; off < 128; off <<= 1) {
        int u = (t < 128 && t >= off) ? sc[t - off] : 0;
        __syncthreads();
        if (t < 128) sc[t] += u;
        __syncthreads();
    }
    if (t < 128) {
        int start = rS + sc[t] - lcnt[t];
        lrp[t] = start;
        int d = d0 + t;
        if (d < NN) rowptr[d] = start;
    }
    __syncthreads();
#pragma unroll
    for (int k = 0; k < 14; k++) {
        int i = t + k * 256;
        if (i < n) {
            unsigned p = pk[k];
            int dl = p >> 17;
            int pos = lrp[dl] + atomicAdd(&cnt[dl], 1);
            e_src[pos] = p & 0x1FFFFu;
        }
    }
}

// ---------- fused BNfin(64-slot) + BN-apply + Linear+ReLU + GATw + att dots
// v5: wave-uniform weights via scalar loads (SMEM pipe); LDS 27.6 KB.
__global__ __launch_bounds__(256) void k_fused(const float* __restrict__ x,
                                               const float* __restrict__ stats, // [64][256]
                                               const float* __restrict__ gamma,
                                               const float* __restrict__ beta,
                                               const float* __restrict__ W1, // [32,128]
                                               const float* __restrict__ b1, // [32]
                                               const float* __restrict__ W2, // [128,32]
                                               const float* __restrict__ aS, // [4,32]
                                               const float* __restrict__ aD, // [4,32]
                                               unsigned* __restrict__ h,     // [N,64] packed
                                               float* __restrict__ asrc,     // [N,4]
                                               float* __restrict__ adst) {   // [N,4]
    __shared__ unsigned xb2[64 * X2S];            // 17152 B
    __shared__ float yt[64 * YS];                 //  8448 B
    __shared__ float ssl[256];                    //  1024 B
    int tid = threadIdx.x;
    int node0 = blockIdx.x * 64;
    int nNodes = min(64, NN - node0);

    if (tid < 128) {
        float s = 0.f, q = 0.f;
        for (int sl = 0; sl < NSLOT; sl++) {
            s += stats[sl * 256 + tid];
            q += stats[sl * 256 + HCC + tid];
        }
        float mean = s * (1.0f / NN);
        float var  = q * (1.0f / NN) - mean * mean;
        float sc   = gamma[tid] * rsqrtf(var + BN_EPS);
        ssl[tid]       = sc;
        ssl[HCC + tid] = beta[tid] - mean * sc;
    }
    __syncthreads();   // ssl read cross-wave below

    // stage x tile: BN-apply then pack to bf16 pairs
    {
        int cS = (tid * 4) & 127;
        float4 scv = *(const float4*)&ssl[cS];
        float4 shv = *(const float4*)&ssl[HCC + cS];
        for (int f4 = tid; f4 < nNodes * 32; f4 += 256) {
            int f = f4 * 4; int n = f >> 7; int c = f & 127;
            float4 xv = *(const float4*)(x + (size_t)(node0 + n) * HCC + c);
            float v0 = xv.x * scv.x + shv.x;
            float v1 = xv.y * scv.y + shv.y;
            float v2 = xv.z * scv.z + shv.z;
            float v3 = xv.w * scv.w + shv.w;
            unsigned* dst = &xb2[n * X2S + (c >> 1)];
            dst[0] = f2bf_pack(v0, v1);
            dst[1] = f2bf_pack(v2, v3);
        }
    }
    __syncthreads();

    int lane = tid & 63;
    // wave index forced into an SGPR: weight indices provably wave-uniform.
    int wv = __builtin_amdgcn_readfirstlane(tid >> 6);
    int n = lane;

    // ---- stage 1: y[n][j0..j0+7] (weights via scalar loads)
    {
        int j0 = wv * 8;
        const float* w1p = W1 + j0 * 128;
        float acc[8];
#pragma unroll
        for (int k = 0; k < 8; k++) acc[k] = b1[j0 + k];
        if (n < nNodes) {
            for (int cb = 0; cb < 128; cb += 4) {
                unsigned p0 = xb2[n * X2S + (cb >> 1)];
                unsigned p1 = xb2[n * X2S + (cb >> 1) + 1];
                float xv0 = bf_lo(p0), xv1 = bf_hi(p0);
                float xv2 = bf_lo(p1), xv3 = bf_hi(p1);
#pragma unroll
                for (int k = 0; k < 8; k++) {
                    float4 w = *(const float4*)&w1p[k * 128 + cb];
                    acc[k] += xv0 * w.x + xv1 * w.y + xv2 * w.z + xv3 * w.w;
                }
            }
#pragma unroll
            for (int k = 0; k < 8; k++) yt[n * YS + j0 + k] = fmaxf(acc[k], 0.f);
        }
    }
    __syncthreads();

    // ---- stage 2: h[n][k0..k0+31] (bf16), head hd = wv (weights via s_load)
    if (n < nNodes) {
        int k0 = wv * 32, hd = wv;
        const float* w2p = W2 + k0 * 32;
        const float* aSp = aS + hd * 32;
        const float* aDp = aD + hd * 32;
        float yreg[32];
#pragma unroll
        for (int j = 0; j < 32; j++) yreg[j] = yt[n * YS + j];
        float sa = 0.f, da = 0.f;
        unsigned* hrow = h + (size_t)(node0 + n) * 64;
        for (int kb = 0; kb < 32; kb += 8) {
            float acck[8];
#pragma unroll
            for (int kk = 0; kk < 8; kk++) acck[kk] = 0.f;
#pragma unroll
            for (int j = 0; j < 32; j += 4) {
#pragma unroll
                for (int kk = 0; kk < 8; kk++) {
                    float4 w = *(const float4*)&w2p[(kb + kk) * 32 + j];
                    acck[kk] += yreg[j] * w.x + yreg[j + 1] * w.y +
                                yreg[j + 2] * w.z + yreg[j + 3] * w.w;
                }
            }
#pragma unroll
            for (int kk = 0; kk < 8; kk++) {
                sa += acck[kk] * aSp[kb + kk];
                da += acck[kk] * aDp[kb + kk];
            }
            uint4 pk;
            pk.x = f2bf_pack(acck[0], acck[1]);
            pk.y = f2bf_pack(acck[2], acck[3]);
            pk.z = f2bf_pack(acck[4], acck[5]);
            pk.w = f2bf_pack(acck[6], acck[7]);
            *(uint4*)(hrow + ((kb) >> 1) + (k0 >> 1)) = pk;
        }
        asrc[(node0 + n) * 4 + hd] = sa;
        adst[(node0 + n) * 4 + hd] = da;
    }
}

// -------- gather-aggregate v5 (lean epilogue, no spill):
// one 16-lane group per dst node; 4 independent nodes per wave.
__global__ __launch_bounds__(256) void k_agg(const int* __restrict__ rowptr,
                                             const int* __restrict__ e_src,
                                             const float* __restrict__ asrc,
                                             const float* __restrict__ adst,
                                             const unsigned* __restrict__ h, // [N,64]
                                             const float* __restrict__ gat_b,
                                             float* __restrict__ xo,
                                             float* __restrict__ stats,      // [64][256]
                                             int do_stats) {
    int tid = threadIdx.x, lane = tid & 63, wv = tid >> 6;
    int g  = lane >> 4;        // node group 0..3
    int li = lane & 15;        // lane within group: channels 8li..8li+7
    int hd = li >> 2;          // head of this channel block
    int d  = blockIdx.x * 16 + wv * 4 + g;     // grid is exactly NN/16

    float4 bA = *(const float4*)(gat_b + li * 8);
    float4 bB = *(const float4*)(gat_b + li * 8 + 4);

    int begin = rowptr[d];
    int end   = rowptr[d + 1];
    float adv = adst[d * 4 + hd];
    float asl = asrc[d * 4 + hd];
    uint4 hs  = *(const uint4*)(h + (size_t)d * 64 + li * 4);

    float acc[8];
#pragma unroll
    for (int k = 0; k < 8; k++) acc[k] = 0.f;
    float ws = 0.f;

    int s[4];
    if (begin < end) {
#pragma unroll
        for (int t = 0; t < 4; t++) s[t] = e_src[min(begin + t, end - 1)];
    }

    for (int j = begin; j < end; j += 4) {
        uint4 hv[4];
#pragma unroll
        for (int t = 0; t < 4; t++) hv[t] = *(const uint4*)(h + (size_t)s[t] * 64 + li * 4);
        float av[4];
#pragma unroll
        for (int t = 0; t < 4; t++) av[t] = asrc[s[t] * 4 + hd];
        // prefetch next indices (independent of current gathers)
        int jn = j + 4;
        int sn[4];
#pragma unroll
        for (int t = 0; t < 4; t++) sn[t] = s[t];
        if (jn < end) {
#pragma unroll
            for (int t = 0; t < 4; t++) sn[t] = e_src[min(jn + t, end - 1)];
        }
        float w[4];
#pragma unroll
        for (int t = 0; t < 4; t++) {
            float l = av[t] + adv; l = l > 0.f ? l : 0.2f * l;
            w[t] = (j + t < end) ? __expf(l) : 0.f;
        }
#pragma unroll
        for (int t = 0; t < 4; t++) {
            acc[0] += w[t] * bf_lo(hv[t].x); acc[1] += w[t] * bf_hi(hv[t].x);
            acc[2] += w[t] * bf_lo(hv[t].y); acc[3] += w[t] * bf_hi(hv[t].y);
            acc[4] += w[t] * bf_lo(hv[t].z); acc[5] += w[t] * bf_hi(hv[t].z);
            acc[6] += w[t] * bf_lo(hv[t].w); acc[7] += w[t] * bf_hi(hv[t].w);
            ws += w[t];
        }
#pragma unroll
        for (int t = 0; t < 4; t++) s[t] = sn[t];
    }

    // self loop
    {
        float l = asl + adv; l = l > 0.f ? l : 0.2f * l;
        float w = __expf(l);
        acc[0] += w * bf_lo(hs.x); acc[1] += w * bf_hi(hs.x);
        acc[2] += w * bf_lo(hs.y); acc[3] += w * bf_hi(hs.y);
        acc[4] += w * bf_lo(hs.z); acc[5] += w * bf_hi(hs.z);
        acc[6] += w * bf_lo(hs.w); acc[7] += w * bf_hi(hs.w);
        ws += w;
    }

    float inv = 1.0f / (ws + 1e-16f);
    float o[8];
    o[0] = acc[0] * inv + bA.x; o[1] = acc[1] * inv + bA.y;
    o[2] = acc[2] * inv + bA.z; o[3] = acc[3] * inv + bA.w;
    o[4] = acc[4] * inv + bB.x; o[5] = acc[5] * inv + bB.y;
    o[6] = acc[6] * inv + bB.z; o[7] = acc[7] * inv + bB.w;
    float* orow = xo + (size_t)d * HCC + li * 8;
    *(float4*)orow       = make_float4(o[0], o[1], o[2], o[3]);
    *(float4*)(orow + 4) = make_float4(o[4], o[5], o[6], o[7]);

    if (!do_stats) return;
    __shared__ float redS[16 * 128], redQ[16 * 128];
    int r = wv * 4 + g;
#pragma unroll
    for (int k = 0; k < 8; k++) {
        redS[r * 128 + li * 8 + k] = o[k];
        redQ[r * 128 + li * 8 + k] = o[k] * o[k];
    }
    __syncthreads();
    int slot = blockIdx.x & (NSLOT - 1);
    if (tid < 128) {
        float v = 0.f;
#pragma unroll
        for (int rr = 0; rr < 16; rr++) v += redS[rr * 128 + tid];
        atomicAdd(&stats[slot * 256 + tid], v);
    } else {
        int c = tid - 128;
        float v = 0.f;
#pragma unroll
        for (int rr = 0; rr < 16; rr++) v += redQ[rr * 128 + c];
        atomicAdd(&stats[slot * 256 + HCC + c], v);
    }
}

// ------------- readout phase A: per-graph channel sums
__global__ __launch_bounds__(256) void k_pool(const float* __restrict__ x,
                                              const int* __restrict__ batch,
                                              float* __restrict__ gsum,  // [G,128]
                                              float* __restrict__ gcnt) {// [G]
    int nb = blockIdx.x * 64, t = threadIdx.x;
    int c = t & 127, half = t >> 7;
    float s = 0.f, cnt = 0.f;
    int curg = -1;
    for (int k = half; k < 64; k += 2) {
        int n = nb + k;
        if (n >= NN) break;
        int g = batch[n];
        if (g != curg) {
            if (curg >= 0) {
                atomicAdd(&gsum[curg * HCC + c], s);
                if (c == 0) atomicAdd(&gcnt[curg], cnt);
            }
            curg = g; s = 0.f; cnt = 0.f;
        }
        s += x[(size_t)n * HCC + c];
        cnt += 1.f;
    }
    if (curg >= 0) {
        atomicAdd(&gsum[curg * HCC + c], s);
        if (c == 0) atomicAdd(&gcnt[curg], cnt);
    }
}

// ------------- readout phase B: out[g] = W·gsum[g] + cnt[g]·b  (tiny GEMV)
__global__ __launch_bounds__(128) void k_out(const float* __restrict__ gsum,
                                             const float* __restrict__ gcnt,
                                             const float* __restrict__ W,  // [10,128]
                                             const float* __restrict__ bb, // [10]
                                             float* __restrict__ out) {    // [G,10]
    __shared__ float v[128];
    int g = blockIdx.x, t = threadIdx.x;
    v[t] = gsum[g * HCC + t];
    __syncthreads();
    if (t < NOUT) {
        float acc = gcnt[g] * bb[t];
        const float* wr = W + t * HCC;
        for (int c = 0; c < HCC; c++) acc += v[c] * wr[c];
        out[g * NOUT + t] = acc;
    }
}

extern "C" void kernel_launch(void* const* d_in, const int* in_sizes, int n_in,
                              void* d_out, int out_size, void* d_ws, size_t ws_size,
                              hipStream_t stream) {
    const int*   x_idx = (const int*)d_in[0];
    const int*   ei    = (const int*)d_in[1];
    const int*   batch = (const int*)d_in[2];
    const float* embed = (const float*)d_in[3];
    const float* bn_g  = (const float*)d_in[4];
    const float* bn_b  = (const float*)d_in[5];
    const float* lin_W = (const float*)d_in[6];
    const float* lin_b = (const float*)d_in[7];
    const float* gat_W = (const float*)d_in[8];
    const float* att_s = (const float*)d_in[9];
    const float* att_d = (const float*)d_in[10];
    const float* gat_b = (const float*)d_in[11];
    const float* ro_W  = (const float*)d_in[12];
    const float* ro_b  = (const float*)d_in[13];
    float* out = (float*)d_out;

    // workspace layout (stats | gsum | gcnt | bkcnt contiguous -> single memset)
    const size_t STG = (size_t)NSLOT * 256;                // floats per stats stage
    float*    x     = (float*)d_ws;                        // [N,128] fp32
    unsigned* h     = (unsigned*)(x + (size_t)NN * HCC);   // [N,64] packed bf16
    float*    asrc  = (float*)(h + (size_t)NN * 64);       // [N,4]
    float*    adst  = asrc + (size_t)NN * NHD;             // [N,4]
    float*    stats = adst + (size_t)NN * NHD;             // [3][64][256]
    float*    gsum  = stats + 3 * STG;                     // [G,128]
    float*    gcnt  = gsum + (size_t)NG * HCC;             // [G]
    int*      bkcnt  = (int*)(gcnt + NG);                  // [NBUK] (memset 0)
    int*      bbase  = bkcnt + NBUK;                       // [NBUK]
    int*      bcnt   = bbase + NBUK;                       // [NBUK]
    int*      rowptr = bcnt + NBUK;                        // [N+1]
    unsigned* e_src  = (unsigned*)(rowptr + NN + 1);       // [E]

    hipMemsetAsync(stats, 0,
                   (3 * STG + (size_t)NG * HCC + NG) * sizeof(float) + NBUK * sizeof(int),
                   stream);

    k_embed_stats<<<512, 256, 0, stream>>>(x_idx, embed, x, stats);
    k_bhist<<<(NE + EB - 1) / EB, 256, 0, stream>>>(ei, bkcnt);
    k_bscan<<<1, 512, 0, stream>>>(bkcnt, bbase, bcnt, rowptr);
    k_bin<<<(NE + EB - 1) / EB, 256, 0, stream>>>(ei, bcnt, e_src);
    k_place<<<NBUK, 256, 0, stream>>>(bbase, e_src, rowptr);

    for (int l = 0; l < NL; ++l) {
        k_fused<<<(NN + 63) / 64, 256, 0, stream>>>(x, stats + l * STG,
                                                    bn_g + l * HCC, bn_b + l * HCC,
                                                    lin_W + l * CC * HCC, lin_b + l * CC,
                                                    gat_W + l * HCC * CC,
                                                    att_s + l * NHD * CC,
                                                    att_d + l * NHD * CC,
                                                    h, asrc, adst);
        k_agg<<<NN / 16, 256, 0, stream>>>(rowptr, (const int*)e_src, asrc, adst, h,
                                           gat_b + l * HCC, x,
                                           stats + (l + 1) * STG,
                                           (l < NL - 1) ? 1 : 0);
    }

    k_pool<<<(NN + 63) / 64, 256, 0, stream>>>(x, batch, gsum, gcnt);
    k_out<<<NG, 128, 0, stream>>>(gsum, gcnt, ro_W, ro_b, out);
}